// Round 7
// baseline (77.891 us; speedup 1.0000x reference)
//
#include <hip/hip_runtime.h>
#include <math.h>

#define SIZE 512
#define NPTS 128

__global__ __launch_bounds__(256) void contour_mask_kernel(
    const float* __restrict__ contour, float* __restrict__ out)
{
    __shared__ float2 c[NPTS];

    const int tid = threadIdx.x;
    if (tid < NPTS) {
        // contour is (128, 2) row-major: [x0, y0, x1, y1, ...]
        c[tid] = ((const float2*)contour)[tid];
    }
    __syncthreads();

    // One block per image row (i = blockIdx.x); each thread does two pixels
    // of that row: columns tid and tid+256. Same mx for both -> shared bx.
    const int i  = blockIdx.x;
    const int j0 = tid;
    const int j1 = tid + 256;
    const int p0 = i * SIZE + j0;
    const int p1 = i * SIZE + j1;

    const float mx  = (float)i  * (1.0f / SIZE);
    const float my0 = (float)j0 * (1.0f / SIZE);
    const float my1 = (float)j1 * (1.0f / SIZE);

    const float K    = 100000.0f;
    const float PI_F = 3.14159265358979f;
    const float HPI  = 1.57079632679490f;
    // acos(1-1e-5), acos(-1+1e-5): the reference's eps-clip mapped to angle space
    const float ANG_LO = 4.4721397e-3f;
    const float ANG_HI = 3.1371205f;
    // |cross| >= CTHR  =>  |tanh(K*cross) - sign(cross)| <= 1-tanh(6) = 1.2e-5
    const float CTHR = 6e-5f;

    // diff at segment start (x-component shared between the two pixels)
    float ax  = c[0].x - mx;
    float ay0 = c[0].y - my0;
    float ay1 = c[0].y - my1;

    float acc0 = 0.0f, acc1 = 0.0f;

    #pragma unroll 4
    for (int n = 0; n < NPTS; ++n) {
        const int n1 = (n + 1) & (NPTS - 1);
        const float2 cn = c[n1];              // wave-uniform LDS broadcast
        const float bx  = cn.x - mx;          // shared between both pixels
        const float by0 = cn.y - my0;
        const float by1 = cn.y - my1;

        // cross = diff.y*roll.x - diff.x*roll.y ; dot = diff . roll
        const float cr0 = fmaf(ay0, bx, -ax * by0);
        const float dt0 = fmaf(ax,  bx,  ay0 * by0);
        const float cr1 = fmaf(ay1, bx, -ax * by1);
        const float dt1 = fmaf(ax,  bx,  ay1 * by1);

        // unsigned angle via atan2(|cr|, dt), octant-reduced:
        //   t = min/max, atan poly on [0,1], swap if |cr|>|dt|, reflect if dt<0
        const float ac0 = fabsf(cr0), ad0 = fabsf(dt0);
        const float ac1 = fabsf(cr1), ad1 = fabsf(dt1);
        const float mn0 = fminf(ac0, ad0), mx0_ = fmaxf(ac0, ad0);
        const float mn1 = fminf(ac1, ad1), mx1_ = fmaxf(ac1, ad1);
        const float t0 = mn0 * __builtin_amdgcn_rcpf(mx0_);
        const float t1 = mn1 * __builtin_amdgcn_rcpf(mx1_);
        const float s0 = t0 * t0;
        const float s1 = t1 * t1;

        // atan(t) ~= t * P(t^2), degree-11 odd minimax on [0,1], |err|~1e-5
        float q0 = fmaf(-0.01172120f, s0, 0.05265332f);
        float q1 = fmaf(-0.01172120f, s1, 0.05265332f);
        q0 = fmaf(q0, s0, -0.11643287f);  q1 = fmaf(q1, s1, -0.11643287f);
        q0 = fmaf(q0, s0,  0.19354346f);  q1 = fmaf(q1, s1,  0.19354346f);
        q0 = fmaf(q0, s0, -0.33262347f);  q1 = fmaf(q1, s1, -0.33262347f);
        q0 = fmaf(q0, s0,  0.99997726f);  q1 = fmaf(q1, s1,  0.99997726f);
        float a0 = t0 * q0;
        float a1 = t1 * q1;

        a0 = (ac0 > ad0) ? (HPI - a0) : a0;
        a1 = (ac1 > ad1) ? (HPI - a1) : a1;
        a0 = (dt0 < 0.0f) ? (PI_F - a0) : a0;
        a1 = (dt1 < 0.0f) ? (PI_F - a1) : a1;

        // replicate reference's cos-clip: clamp angle to [acos(1-eps), acos(-1+eps)]
        a0 = __builtin_amdgcn_fmed3f(a0, ANG_LO, ANG_HI);
        a1 = __builtin_amdgcn_fmed3f(a1, ANG_LO, ANG_HI);

        // sign = tanh(K*cross); outside the thin band it's sign(cross) to 1.2e-5
        if (__any(fminf(ac0, ac1) < CTHR)) {
            const float e0 = __expf(2.0f * K * cr0);
            const float e1 = __expf(2.0f * K * cr1);
            const float sg0 = fmaf(-2.0f, __builtin_amdgcn_rcpf(e0 + 1.0f), 1.0f);
            const float sg1 = fmaf(-2.0f, __builtin_amdgcn_rcpf(e1 + 1.0f), 1.0f);
            acc0 = fmaf(sg0, a0, acc0);
            acc1 = fmaf(sg1, a1, acc1);
        } else {
            acc0 += __builtin_copysignf(a0, cr0);
            acc1 += __builtin_copysignf(a1, cr1);
        }

        ax = bx; ay0 = by0; ay1 = by1;
    }

    float r0 = acc0 * (1.0f / (2.0f * PI_F));
    float r1 = acc1 * (1.0f / (2.0f * PI_F));
    out[p0] = __builtin_amdgcn_fmed3f(r0, 0.0f, 1.0f);
    out[p1] = __builtin_amdgcn_fmed3f(r1, 0.0f, 1.0f);
}

extern "C" void kernel_launch(void* const* d_in, const int* in_sizes, int n_in,
                              void* d_out, int out_size, void* d_ws, size_t ws_size,
                              hipStream_t stream) {
    const float* contour = (const float*)d_in[0];
    float* out = (float*)d_out;

    const int block = 256;
    const int grid  = SIZE;          // one block per row, 2 px per thread

    contour_mask_kernel<<<grid, block, 0, stream>>>(contour, out);
}

// Round 8
// 76.108 us; speedup vs baseline: 1.0234x; 1.0234x over previous
//
#include <hip/hip_runtime.h>
#include <math.h>

#define SIZE 512
#define NPTS 128

__global__ __launch_bounds__(256) void contour_mask_kernel(
    const float* __restrict__ contour, float* __restrict__ out)
{
    __shared__ float2 c[NPTS];

    const int tid = threadIdx.x;
    if (tid < NPTS) {
        // contour is (128, 2) row-major: [x0, y0, x1, y1, ...]
        c[tid] = ((const float2*)contour)[tid];
    }
    __syncthreads();

    const int p = blockIdx.x * 256 + tid;
    const int i = p >> 9;         // row  (first meshgrid coord)
    const int j = p & (SIZE - 1); // col  (second meshgrid coord)

    const float mx = (float)i * (1.0f / SIZE);
    const float my = (float)j * (1.0f / SIZE);

    const float K    = 100000.0f;
    const float PI_F = 3.14159265358979f;
    const float HPI  = 1.57079632679490f;
    // reference's eps-clip on cos, mapped to angle space (acos monotone):
    // clamp(angle, acos(1-eps), acos(-1+eps))
    const float ANG_LO = 4.4721397e-3f;
    const float ANG_HI = 3.1371205f;
    // |cross| >= CTHR  =>  |tanh(K*cross) - sign(cross)| <= 1-tanh(6) = 1.2e-5
    const float CTHR = 6e-5f;

    // diff at segment start, carried across iterations
    float ax = c[0].x - mx;
    float ay = c[0].y - my;

    float acc = 0.0f;

    #pragma unroll 8
    for (int n = 0; n < NPTS; ++n) {
        const int n1 = (n + 1) & (NPTS - 1);
        const float2 cn = c[n1];              // wave-uniform LDS broadcast
        const float bx = cn.x - mx;
        const float by = cn.y - my;

        // cross = diff.y*roll.x - diff.x*roll.y ; dot = diff . roll
        const float cr = fmaf(ay, bx, -ax * by);
        const float dt = fmaf(ax, bx,  ay * by);

        // unsigned angle = atan2(|cr|, dt), octant-reduced:
        // t = min/max (abs folds into VOP3 src modifiers), poly on [0,1]
        const float acr = fabsf(cr), adt = fabsf(dt);
        const float mn  = fminf(acr, adt);
        const float mxv = fmaxf(acr, adt);
        const float t   = mn * __builtin_amdgcn_rcpf(mxv);
        const float s2  = t * t;

        // atan(t) ~= t * P(t^2), degree-11 odd minimax on [0,1], |err|~1e-5
        float q = fmaf(-0.01172120f, s2, 0.05265332f);
        q = fmaf(q, s2, -0.11643287f);
        q = fmaf(q, s2,  0.19354346f);
        q = fmaf(q, s2, -0.33262347f);
        q = fmaf(q, s2,  0.99997726f);
        float a = t * q;

        a = (acr > adt) ? (HPI - a) : a;     // octant swap
        a = (dt < 0.0f) ? (PI_F - a) : a;    // reflect into [0, pi]
        a = __builtin_amdgcn_fmed3f(a, ANG_LO, ANG_HI);

        // sign = tanh(K*cross); outside the thin band it's sign(cross) to 1.2e-5.
        // Wave-uniform branch: slow path ~0.2% of wave-iterations.
        if (__any(acr < CTHR)) {
            const float e  = __expf(2.0f * K * cr);
            const float sg = fmaf(-2.0f, __builtin_amdgcn_rcpf(e + 1.0f), 1.0f);
            acc = fmaf(sg, a, acc);
        } else {
            acc += __builtin_copysignf(a, cr);   // v_bfi + v_add
        }

        ax = bx; ay = by;
    }

    float r = acc * (1.0f / (2.0f * PI_F));
    out[p] = __builtin_amdgcn_fmed3f(r, 0.0f, 1.0f);
}

extern "C" void kernel_launch(void* const* d_in, const int* in_sizes, int n_in,
                              void* d_out, int out_size, void* d_ws, size_t ws_size,
                              hipStream_t stream) {
    const float* contour = (const float*)d_in[0];
    float* out = (float*)d_out;

    const int total = SIZE * SIZE;   // 262144
    const int block = 256;
    const int grid  = total / block; // 1024 blocks -> 4096 waves, 4/SIMD

    contour_mask_kernel<<<grid, block, 0, stream>>>(contour, out);
}